// Round 5
// baseline (175.130 us; speedup 1.0000x reference)
//
#include <hip/hip_runtime.h>
#include <math.h>

#define NBOX 4096
#define TILE 32
#define NT (NBOX / TILE)               // 128
#define NTRI (NT * (NT + 1) / 2)       // 8256 upper-triangle tiles
#define NBLK (NTRI / 4)                // 2064 WGs, 4 tiles per 256-thread WG
#define SS 12                          // struct stride in floats (48 B)
#define JB 400                         // J region base within a slice
#define SLICE 800                      // floats per tile slice (I@0, J@JB)

typedef float v2f __attribute__((ext_vector_type(2)));
typedef float vf4 __attribute__((ext_vector_type(4)));

// LDS per-box layout (10 used floats, stride 12), packed for v_pk_fma_f32:
// [0]a0x [1]a1x [2]a0y [3]a1y | [4]sc0 [5]sc1 [6]l0 [7]l1 | [8]cx [9]cy

struct Box {
    v2f A0, A1, SC, LL;
    float cx, cy;
};

__device__ __forceinline__ float rcp_fast(float x) { return __builtin_amdgcn_rcpf(x); }
__device__ __forceinline__ v2f splat(float s) { return (v2f){s, s}; }
__device__ __forceinline__ v2f fma2(v2f a, v2f b, v2f c) { return __builtin_elementwise_fma(a, b, c); }
__device__ __forceinline__ v2f abs2(v2f a) { return __builtin_elementwise_abs(a); }
__device__ __forceinline__ v2f min2(v2f a, v2f b) { return __builtin_elementwise_min(a, b); }

// Exact identities: overlap r = min(H1, H2, (H1+H2)/2 - |D|)  (signed)
//                   giou1d  g = r / (S - r),  S = H1 + H2 > 0,  r <= S/2
// Single-division tail: m_i = r_i * P / S_i with P = S0*S1*S2*S3.
// x/(P-x) is increasing, so min_i g_i = m*/(P - m*) with m* = min_i m_i.
// r <= S/2 => P - m* >= P/2 (no cancellation); P <= ~243^4 = 3.5e9 (f32 ok).
__device__ __forceinline__ float mgiou_pair(const Box& I, const Box& J) {
    v2f dA = fma2(I.A0, splat(J.A0.x), I.A1 * J.A1.x);   // (u0.v0, u1.v0)
    v2f dB = fma2(I.A0, splat(J.A0.y), I.A1 * J.A1.y);   // (u0.v1, u1.v1)
    v2f DI = fma2(I.A0, splat(J.cx), fma2(I.A1, splat(J.cy), -I.SC));
    v2f DJ = fma2(J.A0, splat(I.cx), fma2(J.A1, splat(I.cy), -J.SC));
    v2f aA = abs2(dA), aB = abs2(dB);
    v2f HI = aA + aB;                                   // J extents on I axes
    v2f HJ = (v2f){aA.x, aB.x} + (v2f){aA.y, aB.y};     // I extents on J axes
    v2f SI = I.LL + HI;
    v2f SJ = J.LL + HJ;
    v2f uI = fma2(splat(0.5f), SI, -abs2(DI));
    v2f uJ = fma2(splat(0.5f), SJ, -abs2(DJ));
    v2f rI = min2(min2(I.LL, HI), uI);
    v2f rJ = min2(min2(J.LL, HJ), uJ);
    float S01 = SI.x * SI.y, S23 = SJ.x * SJ.y;
    float P = S01 * S23;
    v2f mI = rI * (v2f){SI.y, SI.x} * splat(S23);
    v2f mJ = rJ * (v2f){SJ.y, SJ.x} * splat(S01);
    float mm = fminf(fminf(mI.x, mI.y), fminf(mJ.x, mJ.y));
    return fmaxf(mm, 0.0f) * rcp_fast(P - mm);
}

// Cumulative swizzle (+4 floats per 8-struct octet, monotone, no overlap).
// b128 read cosets for structs 4tx+m, tx=0..7: m=0:{0,16,4,20,8,24,12,28}
// m=1:{12,28,16,0,20,4,24,8} m=2:{24,8,28,12,0,16,4,20} m=3:{4,20,8,24,16,
// 0,28,12} — all 8 distinct 4-bank groups each, 8 lanes broadcast per addr
// -> conflict-free (verified 0 SQ_LDS_BANK_CONFLICT in the 32x32 baseline).
__device__ __forceinline__ int sw_offset(int i) { return i * SS + (i >> 3) * 4; }

__device__ __forceinline__ Box load_box(const float* p) {
    Box b;
    float4 x = *(const float4*)(p);
    float4 y = *(const float4*)(p + 4);
    float2 z = *(const float2*)(p + 8);
    b.A0 = (v2f){x.x, x.y}; b.A1 = (v2f){x.z, x.w};
    b.SC = (v2f){y.x, y.y}; b.LL = (v2f){y.z, y.w};
    b.cx = z.x; b.cy = z.y;
    return b;
}

__device__ __forceinline__ void decode_tri(int k, int& bi, int& bj) {
    bi = (int)((float)(2 * NT + 1 - sqrtf((float)((2 * NT + 1) * (2 * NT + 1) - 8 * k))) * 0.5f);
    if (bi > 0 && k < bi * NT - bi * (bi - 1) / 2) bi--;
    if (k >= (bi + 1) * NT - (bi + 1) * bi / 2) bi++;
    bj = bi + (k - (bi * NT - bi * (bi - 1) / 2));
}

// R17->R18: R17's regression was a launch_bounds(512,8) misinterpretation —
// compiler allocated 32 VGPR (8 *blocks*/EU reading) -> spill storm (FETCH
// 29 MB, WRITE +56 MB scratch). Occupancy theory still untested. This round:
// amdgpu_waves_per_eu(8) (unambiguous VGPR<=64), register diet via J[2]
// column chunks (est ~58 live, conflict-free 4tx+m cosets), vT[2][4],
// 4 tiles per 256-thread WG (NBLK=2064, prologue amortized 4x), single-rcp
// tail. Predict: latency-bound -> 74-76; amortization only -> 78-80;
// structural -> 81; spills (VGPR>64 infeasible) -> >85.
__global__ __launch_bounds__(256) __attribute__((amdgpu_waves_per_eu(8)))
void pairwise_kernel(const float* __restrict__ boxes, float* __restrict__ out) {
    __shared__ float sm[4 * SLICE];     // 4 tile slices x (32 I + 32 J structs)

    int tid = threadIdx.x;
    {   // stage: 256 threads = 4 groups of 64; group sid stages slice sid
        int sid = tid >> 6, loc = tid & 63;
        int kP = 4 * blockIdx.x + sid;
        int biP, bjP; decode_tri(kP, biP, bjP);
        int box = ((loc < TILE) ? biP : bjP) * TILE + (loc & (TILE - 1));
        float cx = boxes[box * 5 + 0];
        float cy = boxes[box * 5 + 1];
        float w  = boxes[box * 5 + 2];
        float h  = boxes[box * 5 + 3];
        float ang = boxes[box * 5 + 4];
        float s, c;
        __sincosf(ang, &s, &c);
        float a0x = w * c, a0y = -w * s;    // full edge vectors (match ref rot)
        float a1x = h * s, a1y =  h * c;
        float sc0 = fmaf(a0x, cx, a0y * cy);
        float sc1 = fmaf(a1x, cx, a1y * cy);
        float* d = &sm[sid * SLICE + ((loc < TILE) ? 0 : JB) + sw_offset(loc & (TILE - 1))];
        ((float4*)d)[0] = make_float4(a0x, a1x, a0y, a1y);
        ((float4*)d)[1] = make_float4(sc0, sc1, w * w, h * h);
        ((float2*)d)[4] = make_float2(cx, cy);
    }
    __syncthreads();

    int w = tid >> 6;           // wave 0..3 handles tile slice w
    int lane = tid & 63;
    int tx = lane & 7;          // j quad: 4tx .. 4tx+3   (32 cols)
    int ty = lane >> 3;         // i quad: 4ty .. 4ty+3   (32 rows)

    int k = 4 * blockIdx.x + w;
    int bi, bj; decode_tri(k, bi, bj);

    const float* base = &sm[w * SLICE];
    const float* ip = base + sw_offset(4 * ty);
    int ibase = bi * TILE, jbase = bj * TILE;
    bool offdiag = (bi != bj);

    #pragma unroll
    for (int c = 0; c < 2; ++c) {       // column chunk: cols 4tx+2c, 4tx+2c+1
        Box J0 = load_box(base + JB + sw_offset(4 * tx + 2 * c));
        Box J1 = load_box(base + JB + sw_offset(4 * tx + 2 * c + 1));
        int jg0 = jbase + 4 * tx + 2 * c;
        float vT0[4], vT1[4];
        #pragma unroll
        for (int kk = 0; kk < 4; ++kk) {
            Box I = load_box(ip + kk * SS);
            int ig = ibase + 4 * ty + kk;
            float v0 = (ig == jg0)     ? 0.0f : mgiou_pair(I, J0);
            float v1 = (ig == jg0 + 1) ? 0.0f : mgiou_pair(I, J1);
            vT0[kk] = v0; vT1[kk] = v1;
            // upper: 8B/lane; chunk pair covers the line, L2 merges
            v2f o = {v0, v1};
            *(v2f*)&out[(size_t)ig * NBOX + jg0] = o;
        }
        if (offdiag) {
            vf4 o0 = {vT0[0], vT0[1], vT0[2], vT0[3]};
            *(vf4*)&out[(size_t)jg0 * NBOX + ibase + 4 * ty] = o0;
            vf4 o1 = {vT1[0], vT1[1], vT1[2], vT1[3]};
            *(vf4*)&out[(size_t)(jg0 + 1) * NBOX + ibase + 4 * ty] = o1;
        }
    }
}

extern "C" void kernel_launch(void* const* d_in, const int* in_sizes, int n_in,
                              void* d_out, int out_size, void* d_ws, size_t ws_size,
                              hipStream_t stream) {
    const float* boxes = (const float*)d_in[0];
    float* out = (float*)d_out;
    pairwise_kernel<<<dim3(NBLK), dim3(256), 0, stream>>>(boxes, out);
}

// Round 6
// 81.437 us; speedup vs baseline: 2.1505x; 2.1505x over previous
//
#include <hip/hip_runtime.h>
#include <math.h>

#define NBOX 4096
#define TILE 32
#define NT (NBOX / TILE)               // 128
#define NTRI (NT * (NT + 1) / 2)       // 8256 upper-triangle tiles
#define NBLK (NTRI / 4)                // 2064 WGs, 4 tiles per 256-thread WG
#define SS 12                          // struct stride in floats (48 B)
#define JB 400                         // J region base within a slice
#define SLICE 800                      // floats per tile slice (I@0, J@JB)

typedef float v2f __attribute__((ext_vector_type(2)));
typedef float vf4 __attribute__((ext_vector_type(4)));

// LDS per-box layout (10 used floats, stride 12), packed for v_pk_fma_f32:
// [0]a0x [1]a1x [2]a0y [3]a1y | [4]sc0 [5]sc1 [6]l0 [7]l1 | [8]cx [9]cy

struct Box {
    v2f A0, A1, SC, LL;
    float cx, cy;
};

__device__ __forceinline__ float rcp_fast(float x) { return __builtin_amdgcn_rcpf(x); }
__device__ __forceinline__ v2f splat(float s) { return (v2f){s, s}; }
__device__ __forceinline__ v2f fma2(v2f a, v2f b, v2f c) { return __builtin_elementwise_fma(a, b, c); }
__device__ __forceinline__ v2f abs2(v2f a) { return __builtin_elementwise_abs(a); }
__device__ __forceinline__ v2f min2(v2f a, v2f b) { return __builtin_elementwise_min(a, b); }

// Exact identities: overlap r = min(H1, H2, (H1+H2)/2 - |D|)  (signed)
//                   giou1d  g = r / (S - r),  S = H1 + H2 > 0,  r <= S/2
// Single-division tail: m_i = r_i * P / S_i with P = S0*S1*S2*S3.
// x/(P-x) is increasing, so min_i g_i = m*/(P - m*) with m* = min_i m_i.
// r <= S/2 => P - m* >= P/2 (no cancellation); P <= ~243^4 = 3.5e9 (f32 ok).
__device__ __forceinline__ float mgiou_pair(const Box& I, const Box& J) {
    v2f dA = fma2(I.A0, splat(J.A0.x), I.A1 * J.A1.x);   // (u0.v0, u1.v0)
    v2f dB = fma2(I.A0, splat(J.A0.y), I.A1 * J.A1.y);   // (u0.v1, u1.v1)
    v2f DI = fma2(I.A0, splat(J.cx), fma2(I.A1, splat(J.cy), -I.SC));
    v2f DJ = fma2(J.A0, splat(I.cx), fma2(J.A1, splat(I.cy), -J.SC));
    v2f aA = abs2(dA), aB = abs2(dB);
    v2f HI = aA + aB;                                   // J extents on I axes
    v2f HJ = (v2f){aA.x, aB.x} + (v2f){aA.y, aB.y};     // I extents on J axes
    v2f SI = I.LL + HI;
    v2f SJ = J.LL + HJ;
    v2f uI = fma2(splat(0.5f), SI, -abs2(DI));
    v2f uJ = fma2(splat(0.5f), SJ, -abs2(DJ));
    v2f rI = min2(min2(I.LL, HI), uI);
    v2f rJ = min2(min2(J.LL, HJ), uJ);
    float S01 = SI.x * SI.y, S23 = SJ.x * SJ.y;
    float P = S01 * S23;
    v2f mI = rI * (v2f){SI.y, SI.x} * splat(S23);
    v2f mJ = rJ * (v2f){SJ.y, SJ.x} * splat(S01);
    float mm = fminf(fminf(mI.x, mI.y), fminf(mJ.x, mJ.y));
    return fmaxf(mm, 0.0f) * rcp_fast(P - mm);
}

// Cumulative swizzle (+4 floats per 8-struct octet, monotone, no overlap).
// b128 read cosets for structs 4tx+m are conflict-free (verified 0
// SQ_LDS_BANK_CONFLICT in the 32x32 baseline); 4tx+2c chunks stay in-family.
__device__ __forceinline__ int sw_offset(int i) { return i * SS + (i >> 3) * 4; }

__device__ __forceinline__ Box load_box(const float* p) {
    Box b;
    float4 x = *(const float4*)(p);
    float4 y = *(const float4*)(p + 4);
    float2 z = *(const float2*)(p + 8);
    b.A0 = (v2f){x.x, x.y}; b.A1 = (v2f){x.z, x.w};
    b.SC = (v2f){y.x, y.y}; b.LL = (v2f){y.z, y.w};
    b.cx = z.x; b.cy = z.y;
    return b;
}

__device__ __forceinline__ void decode_tri(int k, int& bi, int& bj) {
    bi = (int)((float)(2 * NT + 1 - sqrtf((float)((2 * NT + 1) * (2 * NT + 1) - 8 * k))) * 0.5f);
    if (bi > 0 && k < bi * NT - bi * (bi - 1) / 2) bi--;
    if (k >= (bi + 1) * NT - (bi + 1) * bi / 2) bi++;
    bj = bi + (k - (bi * NT - bi * (bi - 1) / 2));
}

// R18->R19: R4/R5 both produced 32-VGPR binaries when asking for 8 waves/EU
// => gfx950 wave64 VGPR pool is ~256/wave-slot (512 SIMD32 rows, wave64
// VGPR = 2 rows). Under that model the 81 us baseline (~84-100 VGPR) runs
// at only TWO waves/SIMD — explaining the 2.7x latency stretch. Correct
// target is 64 VGPR = 4 waves/SIMD: amdgpu_waves_per_eu(4), R5's J[2]
// structure (~58 live) otherwise unchanged. Predict: fits+pool-256 ->
// VGPR=64, FETCH ~0.1MB, dur 74-77; pool-512 -> neutral 81; spills -> >90.
__global__ __launch_bounds__(256) __attribute__((amdgpu_waves_per_eu(4)))
void pairwise_kernel(const float* __restrict__ boxes, float* __restrict__ out) {
    __shared__ float sm[4 * SLICE];     // 4 tile slices x (32 I + 32 J structs)

    int tid = threadIdx.x;
    {   // stage: 256 threads = 4 groups of 64; group sid stages slice sid
        int sid = tid >> 6, loc = tid & 63;
        int kP = 4 * blockIdx.x + sid;
        int biP, bjP; decode_tri(kP, biP, bjP);
        int box = ((loc < TILE) ? biP : bjP) * TILE + (loc & (TILE - 1));
        float cx = boxes[box * 5 + 0];
        float cy = boxes[box * 5 + 1];
        float w  = boxes[box * 5 + 2];
        float h  = boxes[box * 5 + 3];
        float ang = boxes[box * 5 + 4];
        float s, c;
        __sincosf(ang, &s, &c);
        float a0x = w * c, a0y = -w * s;    // full edge vectors (match ref rot)
        float a1x = h * s, a1y =  h * c;
        float sc0 = fmaf(a0x, cx, a0y * cy);
        float sc1 = fmaf(a1x, cx, a1y * cy);
        float* d = &sm[sid * SLICE + ((loc < TILE) ? 0 : JB) + sw_offset(loc & (TILE - 1))];
        ((float4*)d)[0] = make_float4(a0x, a1x, a0y, a1y);
        ((float4*)d)[1] = make_float4(sc0, sc1, w * w, h * h);
        ((float2*)d)[4] = make_float2(cx, cy);
    }
    __syncthreads();

    int w = tid >> 6;           // wave 0..3 handles tile slice w
    int lane = tid & 63;
    int tx = lane & 7;          // j quad: 4tx .. 4tx+3   (32 cols)
    int ty = lane >> 3;         // i quad: 4ty .. 4ty+3   (32 rows)

    int k = 4 * blockIdx.x + w;
    int bi, bj; decode_tri(k, bi, bj);

    const float* base = &sm[w * SLICE];
    const float* ip = base + sw_offset(4 * ty);
    int ibase = bi * TILE, jbase = bj * TILE;
    bool offdiag = (bi != bj);

    #pragma unroll
    for (int c = 0; c < 2; ++c) {       // column chunk: cols 4tx+2c, 4tx+2c+1
        Box J0 = load_box(base + JB + sw_offset(4 * tx + 2 * c));
        Box J1 = load_box(base + JB + sw_offset(4 * tx + 2 * c + 1));
        int jg0 = jbase + 4 * tx + 2 * c;
        float vT0[4], vT1[4];
        #pragma unroll
        for (int kk = 0; kk < 4; ++kk) {
            Box I = load_box(ip + kk * SS);
            int ig = ibase + 4 * ty + kk;
            float v0 = (ig == jg0)     ? 0.0f : mgiou_pair(I, J0);
            float v1 = (ig == jg0 + 1) ? 0.0f : mgiou_pair(I, J1);
            vT0[kk] = v0; vT1[kk] = v1;
            // upper: 8B/lane; chunk pair covers the line, L2 merges
            v2f o = {v0, v1};
            *(v2f*)&out[(size_t)ig * NBOX + jg0] = o;
        }
        if (offdiag) {
            vf4 o0 = {vT0[0], vT0[1], vT0[2], vT0[3]};
            *(vf4*)&out[(size_t)jg0 * NBOX + ibase + 4 * ty] = o0;
            vf4 o1 = {vT1[0], vT1[1], vT1[2], vT1[3]};
            *(vf4*)&out[(size_t)(jg0 + 1) * NBOX + ibase + 4 * ty] = o1;
        }
    }
}

extern "C" void kernel_launch(void* const* d_in, const int* in_sizes, int n_in,
                              void* d_out, int out_size, void* d_ws, size_t ws_size,
                              hipStream_t stream) {
    const float* boxes = (const float*)d_in[0];
    float* out = (float*)d_out;
    pairwise_kernel<<<dim3(NBLK), dim3(256), 0, stream>>>(boxes, out);
}